// Round 1
// baseline (6002.605 us; speedup 1.0000x reference)
//
#include <hip/hip_runtime.h>
#include <hip/hip_bf16.h>
#include <math.h>

constexpr int SEQ = 256;
constexpr int DIM = 768;
constexpr int NH  = 8;
constexpr int HD  = 96;

// ---------------------------------------------------------------------------
// Generic tiled f32 GEMM: C[m,n] = (sum_k A[m,k] * W[n,k] + bias[n]) * scale
// 64x64 tile, BK=16, 256 threads, 4x4 accum per thread.
// blockIdx.z offsets (in floats) support per-head batched GEMM.
// ---------------------------------------------------------------------------
__global__ __launch_bounds__(256) void gemm_kernel(
    const float* __restrict__ A, int lda, long aoz,
    const float* __restrict__ W, int ldw, long woz,
    const float* __restrict__ bias,
    float* __restrict__ C, int ldc, long coz,
    int M, int N, int K, float scale)
{
    A += (long)blockIdx.z * aoz;
    W += (long)blockIdx.z * woz;
    C += (long)blockIdx.z * coz;

    __shared__ float As[16][68];   // transposed tiles: As[k][m], padded
    __shared__ float Ws[16][68];   // Ws[k][n]

    const int bm = blockIdx.y * 64;
    const int bn = blockIdx.x * 64;
    const int tid = threadIdx.x;
    const int tx = tid & 15;       // n-group
    const int ty = tid >> 4;       // m-group

    float acc[4][4] = {};

    for (int k0 = 0; k0 < K; k0 += 16) {
#pragma unroll
        for (int i = 0; i < 4; i++) {
            int idx = tid + i * 256;      // 0..1023
            int r = idx >> 4, c = idx & 15;
            As[c][r] = A[(long)(bm + r) * lda + (k0 + c)];
            Ws[c][r] = W[(long)(bn + r) * ldw + (k0 + c)];
        }
        __syncthreads();
#pragma unroll
        for (int kk = 0; kk < 16; kk++) {
            const float4 a = *(const float4*)&As[kk][ty * 4];
            const float4 w = *(const float4*)&Ws[kk][tx * 4];
            acc[0][0] += a.x * w.x; acc[0][1] += a.x * w.y; acc[0][2] += a.x * w.z; acc[0][3] += a.x * w.w;
            acc[1][0] += a.y * w.x; acc[1][1] += a.y * w.y; acc[1][2] += a.y * w.z; acc[1][3] += a.y * w.w;
            acc[2][0] += a.z * w.x; acc[2][1] += a.z * w.y; acc[2][2] += a.z * w.z; acc[2][3] += a.z * w.w;
            acc[3][0] += a.w * w.x; acc[3][1] += a.w * w.y; acc[3][2] += a.w * w.z; acc[3][3] += a.w * w.w;
        }
        __syncthreads();
    }

    const int n0 = bn + tx * 4;
    float4 bv = make_float4(0.f, 0.f, 0.f, 0.f);
    if (bias) bv = *(const float4*)&bias[n0];
#pragma unroll
    for (int i = 0; i < 4; i++) {
        const int m = bm + ty * 4 + i;
        float4 r;
        r.x = (acc[i][0] + bv.x) * scale;
        r.y = (acc[i][1] + bv.y) * scale;
        r.z = (acc[i][2] + bv.z) * scale;
        r.w = (acc[i][3] + bv.w) * scale;
        *(float4*)&C[(long)m * ldc + n0] = r;
    }
}

// ---------------------------------------------------------------------------
// LayerNorm of pos_emb rows (first SEQ rows), gamma/beta applied.
// ---------------------------------------------------------------------------
__global__ __launch_bounds__(256) void posln_kernel(
    const float* __restrict__ pe, const float* __restrict__ g,
    const float* __restrict__ bb, float* __restrict__ w)
{
    __shared__ float buf[256];
    const int i = blockIdx.x, tid = threadIdx.x;
    const float* row = pe + (long)i * DIM;
    float v0 = row[tid], v1 = row[tid + 256], v2 = row[tid + 512];

    buf[tid] = v0 + v1 + v2;
    __syncthreads();
    for (int off = 128; off > 0; off >>= 1) {
        if (tid < off) buf[tid] += buf[tid + off];
        __syncthreads();
    }
    const float mean = buf[0] * (1.f / 768.f);
    __syncthreads();

    const float d0 = v0 - mean, d1 = v1 - mean, d2 = v2 - mean;
    buf[tid] = d0 * d0 + d1 * d1 + d2 * d2;
    __syncthreads();
    for (int off = 128; off > 0; off >>= 1) {
        if (tid < off) buf[tid] += buf[tid + off];
        __syncthreads();
    }
    const float rstd = rsqrtf(buf[0] * (1.f / 768.f) + 1e-5f);

    float* wr = w + (long)i * DIM;
    wr[tid]       = d0 * rstd * g[tid]       + bb[tid];
    wr[tid + 256] = d1 * rstd * g[tid + 256] + bb[tid + 256];
    wr[tid + 512] = d2 * rstd * g[tid + 512] + bb[tid + 512];
}

// bias[h, ij] += table[rp[ij], h]
__global__ __launch_bounds__(256) void relbias_kernel(
    const float* __restrict__ table, const int* __restrict__ rp,
    float* __restrict__ bias)
{
    const int ij = blockIdx.x * 256 + threadIdx.x;   // over SEQ*SEQ
    const int bucket = rp[ij];
#pragma unroll
    for (int h = 0; h < NH; h++)
        bias[(long)h * SEQ * SEQ + ij] += table[bucket * NH + h];
}

// x[t,:] = embed[tokens[t],:]
__global__ __launch_bounds__(256) void gather_kernel(
    const int* __restrict__ tokens, const float* __restrict__ emb,
    float* __restrict__ x)
{
    const int t = blockIdx.x;
    const int tok = tokens[t];
    const float4* src = (const float4*)(emb + (long)tok * DIM);
    float4* dst = (float4*)(x + (long)t * DIM);
    if (threadIdx.x < 192) dst[threadIdx.x] = src[threadIdx.x];
}

// ---------------------------------------------------------------------------
// Attention: one block per (b, h, 16-row i-tile). f32 throughout.
// ---------------------------------------------------------------------------
__global__ __launch_bounds__(256) void attn_kernel(
    const float* __restrict__ q, const float* __restrict__ k,
    const float* __restrict__ v, const float* __restrict__ bias,
    float* __restrict__ o)
{
    __shared__ float Qs[16][100];     // padded (bank spread for broadcast reads)
    __shared__ float Ps[16][260];     // scores -> exp(scores)
    __shared__ float KV[96 * 68];     // union: Ktc[d][j] (stride 68) / Vs[j*96+d]
    __shared__ float invs[16];

    const int tile = blockIdx.x;
    const int b  = tile >> 7;
    const int h  = (tile >> 4) & 7;
    const int it = tile & 15;
    const int i0 = it << 4;
    const int tid = threadIdx.x;

    const float* qb = q + ((long)(b * SEQ + i0)) * DIM + h * HD;
    const float* kb = k + ((long)b * SEQ) * DIM + h * HD;
    const float* vb = v + ((long)b * SEQ) * DIM + h * HD;
    const float* bb = bias + ((long)(h * SEQ + i0)) * SEQ;
    float* ob       = o + ((long)(b * SEQ + i0)) * DIM + h * HD;

    // stage Q tile: 16 x 96 = 384 float4
    for (int e = tid; e < 384; e += 256) {
        int r = e / 24, c4 = e % 24;
        *(float4*)&Qs[r][c4 * 4] = *(const float4*)&qb[(long)r * DIM + c4 * 4];
    }
    __syncthreads();

    // ---- scores: S[i, j] = q_i . k_j + bias[h,i,j] ----
    const int tx = tid & 15;    // j-group (4 j's)
    const int ty = tid >> 4;    // i (0..15)
    for (int jc = 0; jc < 4; jc++) {
        // stage K chunk transposed: KV[d*68 + j], 64 j x 96 d
        for (int e = tid; e < 6144; e += 256) {
            int j = e / 96, d = e % 96;
            KV[d * 68 + j] = kb[(long)(jc * 64 + j) * DIM + d];
        }
        __syncthreads();
        float s0 = 0.f, s1 = 0.f, s2 = 0.f, s3 = 0.f;
#pragma unroll 4
        for (int d = 0; d < 96; d++) {
            const float qv = Qs[ty][d];
            const float4 kv = *(const float4*)&KV[d * 68 + tx * 4];
            s0 += qv * kv.x; s1 += qv * kv.y; s2 += qv * kv.z; s3 += qv * kv.w;
        }
        const float4 bvv = *(const float4*)&bb[(long)ty * SEQ + jc * 64 + tx * 4];
        float4 sv;
        sv.x = s0 + bvv.x; sv.y = s1 + bvv.y; sv.z = s2 + bvv.z; sv.w = s3 + bvv.w;
        *(float4*)&Ps[ty][jc * 64 + tx * 4] = sv;
        __syncthreads();
    }

    // ---- softmax (16 rows, serial per row — cheap) ----
    if (tid < 16) {
        float m = -1e30f;
        for (int j = 0; j < SEQ; j++) m = fmaxf(m, Ps[tid][j]);
        float sum = 0.f;
        for (int j = 0; j < SEQ; j++) {
            float e = expf(Ps[tid][j] - m);
            Ps[tid][j] = e;
            sum += e;
        }
        invs[tid] = 1.f / sum;
    }
    __syncthreads();

    // ---- O = P . V ----
    const int d4 = tid % 24;          // 4-float group of d
    const int ih = tid / 24;          // 0..7 (valid when tid < 192)
    const int iA = ih * 2, iB = iA + 1;
    float4 accA = make_float4(0.f, 0.f, 0.f, 0.f);
    float4 accB = make_float4(0.f, 0.f, 0.f, 0.f);

    for (int jc = 0; jc < 8; jc++) {
        // stage V chunk natural: KV[j*96 + d], 32 j x 96 d = 768 float4
        for (int e = tid; e < 768; e += 256) {
            int j = e / 24, c4 = e % 24;
            *(float4*)&KV[j * 96 + c4 * 4] = *(const float4*)&vb[(long)(jc * 32 + j) * DIM + c4 * 4];
        }
        __syncthreads();
        if (tid < 192) {
#pragma unroll 4
            for (int j = 0; j < 32; j++) {
                const float4 vv = *(const float4*)&KV[j * 96 + d4 * 4];
                const float pA = Ps[iA][jc * 32 + j];
                const float pB = Ps[iB][jc * 32 + j];
                accA.x += pA * vv.x; accA.y += pA * vv.y; accA.z += pA * vv.z; accA.w += pA * vv.w;
                accB.x += pB * vv.x; accB.y += pB * vv.y; accB.z += pB * vv.z; accB.w += pB * vv.w;
            }
        }
        __syncthreads();
    }

    if (tid < 192) {
        const float ia = invs[iA], ib = invs[iB];
        float4 rA, rB;
        rA.x = accA.x * ia; rA.y = accA.y * ia; rA.z = accA.z * ia; rA.w = accA.w * ia;
        rB.x = accB.x * ib; rB.y = accB.y * ib; rB.z = accB.z * ib; rB.w = accB.w * ib;
        *(float4*)&ob[(long)iA * DIM + d4 * 4] = rA;
        *(float4*)&ob[(long)iB * DIM + d4 * 4] = rB;
    }
}

// out[b,:] = x[b, 0, :]
__global__ __launch_bounds__(256) void out_kernel(
    const float* __restrict__ x, float* __restrict__ out)
{
    const int b = blockIdx.x, tid = threadIdx.x;
    out[b * DIM + tid]       = x[(long)b * SEQ * DIM + tid];
    out[b * DIM + tid + 256] = x[(long)b * SEQ * DIM + tid + 256];
    out[b * DIM + tid + 512] = x[(long)b * SEQ * DIM + tid + 512];
}

extern "C" void kernel_launch(void* const* d_in, const int* in_sizes, int n_in,
                              void* d_out, int out_size, void* d_ws, size_t ws_size,
                              hipStream_t stream)
{
    const int*   tokens   = (const int*)d_in[0];
    const float* embed    = (const float*)d_in[1];
    const float* pos_emb  = (const float*)d_in[2];
    const float* pos_q_w  = (const float*)d_in[3];
    const float* pos_q_b  = (const float*)d_in[4];
    const float* pos_k_w  = (const float*)d_in[5];
    const float* pos_k_b  = (const float*)d_in[6];
    const float* pos_ln_g = (const float*)d_in[7];
    const float* pos_ln_b = (const float*)d_in[8];
    const float* rel_tab  = (const float*)d_in[9];
    const int*   rp       = (const int*)d_in[10];
    const float* Wq = (const float*)d_in[11];
    const float* bq = (const float*)d_in[12];
    const float* Wk = (const float*)d_in[13];
    const float* bk = (const float*)d_in[14];
    const float* Wv = (const float*)d_in[15];
    const float* bv = (const float*)d_in[16];
    const float* Wo = (const float*)d_in[17];
    const float* bo = (const float*)d_in[18];
    float* out = (float*)d_out;

    float* ws = (float*)d_ws;
    const long NT = 32L * SEQ;            // 8192 tokens
    float* x   = ws;
    float* qb_ = x   + NT * DIM;
    float* kb_ = qb_ + NT * DIM;
    float* vb_ = kb_ + NT * DIM;
    float* ob_ = vb_ + NT * DIM;
    float* bias = ob_ + NT * DIM;                 // [H, S, S]
    float* wln = bias + (long)NH * SEQ * SEQ;
    float* pq  = wln + (long)SEQ * DIM;
    float* pk  = pq  + (long)SEQ * DIM;

    const float SCALE = 0.07216878364870322f;     // (HD*2)^-0.5 = 1/sqrt(192)

    // positional bias precompute
    posln_kernel<<<256, 256, 0, stream>>>(pos_emb, pos_ln_g, pos_ln_b, wln);
    gemm_kernel<<<dim3(12, 4, 1), 256, 0, stream>>>(wln, DIM, 0, pos_q_w, DIM, 0, pos_q_b,
                                                    pq, DIM, 0, SEQ, DIM, DIM, SCALE);
    gemm_kernel<<<dim3(12, 4, 1), 256, 0, stream>>>(wln, DIM, 0, pos_k_w, DIM, 0, pos_k_b,
                                                    pk, DIM, 0, SEQ, DIM, DIM, 1.0f);
    // abs_bias[h] = pq_h . pk_h^T  (z = head)
    gemm_kernel<<<dim3(4, 4, NH), 256, 0, stream>>>(pq, DIM, HD, pk, DIM, HD, nullptr,
                                                    bias, SEQ, (long)SEQ * SEQ, SEQ, SEQ, HD, 1.0f);
    relbias_kernel<<<256, 256, 0, stream>>>(rel_tab, rp, bias);

    // token embedding
    gather_kernel<<<8192, 256, 0, stream>>>(tokens, embed, x);

    for (int l = 0; l < 6; l++) {
        const long wOff = (long)l * DIM * DIM, bOff = (long)l * DIM;
        gemm_kernel<<<dim3(12, 128, 1), 256, 0, stream>>>(x, DIM, 0, Wq + wOff, DIM, 0, bq + bOff,
                                                          qb_, DIM, 0, (int)NT, DIM, DIM, SCALE);
        gemm_kernel<<<dim3(12, 128, 1), 256, 0, stream>>>(x, DIM, 0, Wk + wOff, DIM, 0, bk + bOff,
                                                          kb_, DIM, 0, (int)NT, DIM, DIM, 1.f);
        gemm_kernel<<<dim3(12, 128, 1), 256, 0, stream>>>(x, DIM, 0, Wv + wOff, DIM, 0, bv + bOff,
                                                          vb_, DIM, 0, (int)NT, DIM, DIM, 1.f);
        attn_kernel<<<4096, 256, 0, stream>>>(qb_, kb_, vb_, bias, ob_);
        gemm_kernel<<<dim3(12, 128, 1), 256, 0, stream>>>(ob_, DIM, 0, Wo + wOff, DIM, 0, bo + bOff,
                                                          x, DIM, 0, (int)NT, DIM, DIM, 1.f);
    }

    out_kernel<<<32, 256, 0, stream>>>(x, out);
}

// Round 2
// 1151.244 us; speedup vs baseline: 5.2140x; 5.2140x over previous
//
#include <hip/hip_runtime.h>
#include <hip/hip_bf16.h>
#include <math.h>

constexpr int SEQ = 256;
constexpr int DIM = 768;
constexpr int NH  = 8;
constexpr int HD  = 96;

typedef __attribute__((ext_vector_type(8))) short short8;
typedef __attribute__((ext_vector_type(4))) float f32x4;
using bf16 = __hip_bfloat16;

#define ASYNC_COPY16(gptr, lptr) \
  __builtin_amdgcn_global_load_lds((const __attribute__((address_space(1))) void*)(gptr), \
                                   (__attribute__((address_space(3))) void*)(lptr), 16, 0, 0)

// ---------------------------------------------------------------------------
// f32 tiled GEMM (kept for the tiny positional-bias precompute only)
// ---------------------------------------------------------------------------
__global__ __launch_bounds__(256) void gemm_kernel(
    const float* __restrict__ A, int lda, long aoz,
    const float* __restrict__ W, int ldw, long woz,
    const float* __restrict__ bias,
    float* __restrict__ C, int ldc, long coz,
    int M, int N, int K, float scale)
{
    A += (long)blockIdx.z * aoz;
    W += (long)blockIdx.z * woz;
    C += (long)blockIdx.z * coz;

    __shared__ float As[16][68];
    __shared__ float Ws[16][68];

    const int bm = blockIdx.y * 64;
    const int bn = blockIdx.x * 64;
    const int tid = threadIdx.x;
    const int tx = tid & 15;
    const int ty = tid >> 4;

    float acc[4][4] = {};

    for (int k0 = 0; k0 < K; k0 += 16) {
#pragma unroll
        for (int i = 0; i < 4; i++) {
            int idx = tid + i * 256;
            int r = idx >> 4, c = idx & 15;
            As[c][r] = A[(long)(bm + r) * lda + (k0 + c)];
            Ws[c][r] = W[(long)(bn + r) * ldw + (k0 + c)];
        }
        __syncthreads();
#pragma unroll
        for (int kk = 0; kk < 16; kk++) {
            const float4 a = *(const float4*)&As[kk][ty * 4];
            const float4 w = *(const float4*)&Ws[kk][tx * 4];
            acc[0][0] += a.x * w.x; acc[0][1] += a.x * w.y; acc[0][2] += a.x * w.z; acc[0][3] += a.x * w.w;
            acc[1][0] += a.y * w.x; acc[1][1] += a.y * w.y; acc[1][2] += a.y * w.z; acc[1][3] += a.y * w.w;
            acc[2][0] += a.z * w.x; acc[2][1] += a.z * w.y; acc[2][2] += a.z * w.z; acc[2][3] += a.z * w.w;
            acc[3][0] += a.w * w.x; acc[3][1] += a.w * w.y; acc[3][2] += a.w * w.z; acc[3][3] += a.w * w.w;
        }
        __syncthreads();
    }

    const int n0 = bn + tx * 4;
    float4 bv = make_float4(0.f, 0.f, 0.f, 0.f);
    if (bias) bv = *(const float4*)&bias[n0];
#pragma unroll
    for (int i = 0; i < 4; i++) {
        const int m = bm + ty * 4 + i;
        float4 r;
        r.x = (acc[i][0] + bv.x) * scale;
        r.y = (acc[i][1] + bv.y) * scale;
        r.z = (acc[i][2] + bv.z) * scale;
        r.w = (acc[i][3] + bv.w) * scale;
        *(float4*)&C[(long)m * ldc + n0] = r;
    }
}

// ---------------------------------------------------------------------------
// LayerNorm of pos_emb rows
// ---------------------------------------------------------------------------
__global__ __launch_bounds__(256) void posln_kernel(
    const float* __restrict__ pe, const float* __restrict__ g,
    const float* __restrict__ bb, float* __restrict__ w)
{
    __shared__ float buf[256];
    const int i = blockIdx.x, tid = threadIdx.x;
    const float* row = pe + (long)i * DIM;
    float v0 = row[tid], v1 = row[tid + 256], v2 = row[tid + 512];

    buf[tid] = v0 + v1 + v2;
    __syncthreads();
    for (int off = 128; off > 0; off >>= 1) {
        if (tid < off) buf[tid] += buf[tid + off];
        __syncthreads();
    }
    const float mean = buf[0] * (1.f / 768.f);
    __syncthreads();

    const float d0 = v0 - mean, d1 = v1 - mean, d2 = v2 - mean;
    buf[tid] = d0 * d0 + d1 * d1 + d2 * d2;
    __syncthreads();
    for (int off = 128; off > 0; off >>= 1) {
        if (tid < off) buf[tid] += buf[tid + off];
        __syncthreads();
    }
    const float rstd = rsqrtf(buf[0] * (1.f / 768.f) + 1e-5f);

    float* wr = w + (long)i * DIM;
    wr[tid]       = d0 * rstd * g[tid]       + bb[tid];
    wr[tid + 256] = d1 * rstd * g[tid + 256] + bb[tid + 256];
    wr[tid + 512] = d2 * rstd * g[tid + 512] + bb[tid + 512];
}

// bias[h, ij] += table[rp[ij], h]
__global__ __launch_bounds__(256) void relbias_kernel(
    const float* __restrict__ table, const int* __restrict__ rp,
    float* __restrict__ bias)
{
    const int ij = blockIdx.x * 256 + threadIdx.x;
    const int bucket = rp[ij];
#pragma unroll
    for (int h = 0; h < NH; h++)
        bias[(long)h * SEQ * SEQ + ij] += table[bucket * NH + h];
}

// ---------------------------------------------------------------------------
// weight / bias conversion to bf16 (q-scale folded)
// ---------------------------------------------------------------------------
__global__ __launch_bounds__(256) void convert_qkv_kernel(
    const float* __restrict__ Wq, const float* __restrict__ Wk,
    const float* __restrict__ Wv, bf16* __restrict__ wqkv, float scale)
{
    const long idx = (long)blockIdx.x * 256 + threadIdx.x; // over 6*2304*768/4
    const long e = idx * 4;
    const int k = (int)(e % 768);
    const long nl = e / 768;
    const int n = (int)(nl % 2304);
    const int l = (int)(nl / 2304);

    const float* src;
    float sc = 1.f;
    if (n < 768)       { src = Wq + ((long)l * 768 + n) * 768; sc = scale; }
    else if (n < 1536) { src = Wk + ((long)l * 768 + (n - 768)) * 768; }
    else               { src = Wv + ((long)l * 768 + (n - 1536)) * 768; }

    const float4 v = *(const float4*)&src[k];
    bf16 tmp[4];
    tmp[0] = __float2bfloat16(v.x * sc);
    tmp[1] = __float2bfloat16(v.y * sc);
    tmp[2] = __float2bfloat16(v.z * sc);
    tmp[3] = __float2bfloat16(v.w * sc);
    *(uint2*)&wqkv[((long)l * 2304 + n) * 768 + k] = *(uint2*)tmp;
}

__global__ __launch_bounds__(256) void convert_wo_kernel(
    const float* __restrict__ Wo, bf16* __restrict__ wo)
{
    const long idx = (long)blockIdx.x * 256 + threadIdx.x; // over 6*768*768/4
    const long e = idx * 4;
    const float4 v = *(const float4*)&Wo[e];
    bf16 tmp[4];
    tmp[0] = __float2bfloat16(v.x);
    tmp[1] = __float2bfloat16(v.y);
    tmp[2] = __float2bfloat16(v.z);
    tmp[3] = __float2bfloat16(v.w);
    *(uint2*)&wo[e] = *(uint2*)tmp;
}

__global__ __launch_bounds__(256) void convert_bias_kernel(
    const float* __restrict__ bq, const float* __restrict__ bk,
    const float* __restrict__ bv, float* __restrict__ bqkv, float scale)
{
    const int idx = blockIdx.x * 256 + threadIdx.x; // over 6*2304
    const int n = idx % 2304;
    const int l = idx / 2304;
    float v;
    if (n < 768)       v = bq[l * 768 + n] * scale;
    else if (n < 1536) v = bk[l * 768 + (n - 768)];
    else               v = bv[l * 768 + (n - 1536)];
    bqkv[idx] = v;
}

// x_bf[t,:] = bf16(embed[tokens[t],:])
__global__ __launch_bounds__(192) void gather_bf16_kernel(
    const int* __restrict__ tokens, const float* __restrict__ emb,
    bf16* __restrict__ x)
{
    const int t = blockIdx.x;
    const int tok = tokens[t];
    const float4 v = ((const float4*)(emb + (long)tok * DIM))[threadIdx.x];
    bf16 tmp[4];
    tmp[0] = __float2bfloat16(v.x);
    tmp[1] = __float2bfloat16(v.y);
    tmp[2] = __float2bfloat16(v.z);
    tmp[3] = __float2bfloat16(v.w);
    *(uint2*)&x[(long)t * DIM + threadIdx.x * 4] = *(uint2*)tmp;
}

// ---------------------------------------------------------------------------
// bf16 MFMA GEMM: C[m,n] = sum_k A[m,k]*B[n,k] + bias[n]
// 128x128 tile, BK=32, 256 threads (4 waves, each 64x64 = 4x4 MFMA tiles)
// m97-style global_load_lds staging. Cf != null -> write f32, else bf16.
// ---------------------------------------------------------------------------
__global__ __launch_bounds__(256) void gemm_bf16_kernel(
    const bf16* __restrict__ A, const bf16* __restrict__ B,
    const float* __restrict__ bias,
    bf16* __restrict__ Cb, float* __restrict__ Cf,
    int N, int K)
{
    __shared__ bf16 As[128 * 32];
    __shared__ bf16 Bs[128 * 32];

    const int tid = threadIdx.x;
    const int lane = tid & 63, wave = tid >> 6;
    const int wm = wave & 1, wn = wave >> 1;
    const long bm = (long)blockIdx.y * 128, bn = (long)blockIdx.x * 128;
    const int col = lane & 15, quad = lane >> 4;

    const int u0 = tid, u1 = tid + 256;
    const long ga0 = (bm + (u0 >> 2)) * (long)K + (u0 & 3) * 8;
    const long ga1 = (bm + (u1 >> 2)) * (long)K + (u1 & 3) * 8;
    const long gb0 = (bn + (u0 >> 2)) * (long)K + (u0 & 3) * 8;
    const long gb1 = (bn + (u1 >> 2)) * (long)K + (u1 & 3) * 8;

    f32x4 acc[4][4] = {};

    for (int k0 = 0; k0 < K; k0 += 32) {
        ASYNC_COPY16(A + ga0 + k0, &As[u0 * 8]);
        ASYNC_COPY16(A + ga1 + k0, &As[u1 * 8]);
        ASYNC_COPY16(B + gb0 + k0, &Bs[u0 * 8]);
        ASYNC_COPY16(B + gb1 + k0, &Bs[u1 * 8]);
        __syncthreads();

        short8 af[4], bfr[4];
#pragma unroll
        for (int t = 0; t < 4; t++) {
            af[t]  = *(const short8*)&As[(wm * 64 + t * 16 + col) * 32 + quad * 8];
            bfr[t] = *(const short8*)&Bs[(wn * 64 + t * 16 + col) * 32 + quad * 8];
        }
#pragma unroll
        for (int tm = 0; tm < 4; tm++)
#pragma unroll
            for (int tn = 0; tn < 4; tn++)
                acc[tm][tn] = __builtin_amdgcn_mfma_f32_16x16x32_bf16(af[tm], bfr[tn], acc[tm][tn], 0, 0, 0);
        __syncthreads();
    }

#pragma unroll
    for (int tn = 0; tn < 4; tn++) {
        const long n = bn + wn * 64 + tn * 16 + col;
        const float bvv = bias[n];
#pragma unroll
        for (int tm = 0; tm < 4; tm++) {
#pragma unroll
            for (int r = 0; r < 4; r++) {
                const long m = bm + wm * 64 + tm * 16 + quad * 4 + r;
                const float v = acc[tm][tn][r] + bvv;
                if (Cf) Cf[m * N + n] = v;
                else    Cb[m * N + n] = __float2bfloat16(v);
            }
        }
    }
}

// ---------------------------------------------------------------------------
// MFMA attention: block per (b, h, 64-row i-tile); 4 waves x 16 rows.
// qkv: [8192 x 2304] bf16 (q|k|v), q pre-scaled. bias: [8,256,256] f32.
// ---------------------------------------------------------------------------
__global__ __launch_bounds__(256) void attn_mfma_kernel(
    const bf16* __restrict__ qkv, const float* __restrict__ bias,
    bf16* __restrict__ o)
{
    constexpr int QS = 104;   // stride for Qs/Ks (2-way banks, 16B aligned)
    constexpr int PS = 264;   // stride for Ps
    constexpr int VS = 40;    // stride for Vt

    __shared__ bf16 Qs[64 * QS];
    __shared__ bf16 Ks[64 * QS];   // aliased as Vt (96*40 = 3840 < 6656)
    __shared__ bf16 Ps[64 * PS];
    bf16* Vt = Ks;

    const int blk = blockIdx.x;          // 32*8*4
    const int it = blk & 3;
    const int h  = (blk >> 2) & 7;
    const int b  = blk >> 5;
    const int i0 = it * 64;
    const int tid = threadIdx.x, lane = tid & 63, wave = tid >> 6;
    const int col = lane & 15, quad = lane >> 4;
    const long rowbase = (long)b * SEQ;

    // stage Q tile (64 x 96)
    for (int u = tid; u < 768; u += 256) {
        const int r = u / 12, c8 = u % 12;
        *(uint4*)&Qs[r * QS + c8 * 8] =
            *(const uint4*)&qkv[(rowbase + i0 + r) * 2304 + h * 96 + c8 * 8];
    }

    // ---- scores ----
    f32x4 accS[16] = {};
    for (int jc = 0; jc < 4; jc++) {
        __syncthreads();
        for (int u = tid; u < 768; u += 256) {
            const int r = u / 12, c8 = u % 12;
            *(uint4*)&Ks[r * QS + c8 * 8] =
                *(const uint4*)&qkv[(rowbase + jc * 64 + r) * 2304 + 768 + h * 96 + c8 * 8];
        }
        __syncthreads();
#pragma unroll
        for (int ks = 0; ks < 3; ks++) {
            const short8 aq = *(const short8*)&Qs[(wave * 16 + col) * QS + ks * 32 + quad * 8];
#pragma unroll
            for (int jt = 0; jt < 4; jt++) {
                const short8 bk_ = *(const short8*)&Ks[(jt * 16 + col) * QS + ks * 32 + quad * 8];
                accS[jc * 4 + jt] = __builtin_amdgcn_mfma_f32_16x16x32_bf16(aq, bk_, accS[jc * 4 + jt], 0, 0, 0);
            }
        }
    }

    // ---- bias + softmax (rows i0 + wave*16 + quad*4 + r, col jt*16+col) ----
    const float* bb = bias + ((long)h * SEQ + i0 + wave * 16 + quad * 4) * SEQ;
#pragma unroll
    for (int jt = 0; jt < 16; jt++)
#pragma unroll
        for (int r = 0; r < 4; r++)
            accS[jt][r] += bb[r * SEQ + jt * 16 + col];

#pragma unroll
    for (int r = 0; r < 4; r++) {
        float m = accS[0][r];
#pragma unroll
        for (int jt = 1; jt < 16; jt++) m = fmaxf(m, accS[jt][r]);
        for (int d = 1; d < 16; d <<= 1) m = fmaxf(m, __shfl_xor(m, d));
        float s = 0.f;
#pragma unroll
        for (int jt = 0; jt < 16; jt++) {
            const float e = __expf(accS[jt][r] - m);
            accS[jt][r] = e;
            s += e;
        }
        for (int d = 1; d < 16; d <<= 1) s += __shfl_xor(s, d);
        const float inv = 1.f / s;
        const int prow = wave * 16 + quad * 4 + r;
#pragma unroll
        for (int jt = 0; jt < 16; jt++)
            Ps[prow * PS + jt * 16 + col] = __float2bfloat16(accS[jt][r] * inv);
    }

    // ---- O = P.V ----
    f32x4 accO[6] = {};
    for (int kc = 0; kc < 8; kc++) {
        __syncthreads();   // prev Vt reads / Ks reads done
        for (int u = tid; u < 384; u += 256) {
            const int d = u % 96, jq = u / 96;
            bf16 tmp[8];
#pragma unroll
            for (int e = 0; e < 8; e++)
                tmp[e] = qkv[(rowbase + kc * 32 + jq * 8 + e) * 2304 + 1536 + h * 96 + d];
            *(uint4*)&Vt[d * VS + jq * 8] = *(uint4*)tmp;
        }
        __syncthreads();
        const short8 ap = *(const short8*)&Ps[(wave * 16 + col) * PS + kc * 32 + quad * 8];
#pragma unroll
        for (int nt = 0; nt < 6; nt++) {
            const short8 bv_ = *(const short8*)&Vt[(nt * 16 + col) * VS + quad * 8];
            accO[nt] = __builtin_amdgcn_mfma_f32_16x16x32_bf16(ap, bv_, accO[nt], 0, 0, 0);
        }
    }

#pragma unroll
    for (int nt = 0; nt < 6; nt++)
#pragma unroll
        for (int r = 0; r < 4; r++) {
            const long m = rowbase + i0 + wave * 16 + quad * 4 + r;
            o[m * DIM + h * 96 + nt * 16 + col] = __float2bfloat16(accO[nt][r]);
        }
}

// out[b,:] = xf[b, 0, :]
__global__ __launch_bounds__(256) void out_kernel(
    const float* __restrict__ x, float* __restrict__ out)
{
    const int b = blockIdx.x, tid = threadIdx.x;
    out[b * DIM + tid]       = x[(long)b * SEQ * DIM + tid];
    out[b * DIM + tid + 256] = x[(long)b * SEQ * DIM + tid + 256];
    out[b * DIM + tid + 512] = x[(long)b * SEQ * DIM + tid + 512];
}

extern "C" void kernel_launch(void* const* d_in, const int* in_sizes, int n_in,
                              void* d_out, int out_size, void* d_ws, size_t ws_size,
                              hipStream_t stream)
{
    const int*   tokens   = (const int*)d_in[0];
    const float* embed    = (const float*)d_in[1];
    const float* pos_emb  = (const float*)d_in[2];
    const float* pos_q_w  = (const float*)d_in[3];
    const float* pos_q_b  = (const float*)d_in[4];
    const float* pos_k_w  = (const float*)d_in[5];
    const float* pos_k_b  = (const float*)d_in[6];
    const float* pos_ln_g = (const float*)d_in[7];
    const float* pos_ln_b = (const float*)d_in[8];
    const float* rel_tab  = (const float*)d_in[9];
    const int*   rp       = (const int*)d_in[10];
    const float* Wq = (const float*)d_in[11];
    const float* bq = (const float*)d_in[12];
    const float* Wk = (const float*)d_in[13];
    const float* bk = (const float*)d_in[14];
    const float* Wv = (const float*)d_in[15];
    const float* bv = (const float*)d_in[16];
    const float* Wo = (const float*)d_in[17];
    const float* bo = (const float*)d_in[18];
    float* out = (float*)d_out;

    char* p = (char*)d_ws;
    auto alloc = [&](size_t bytes) -> char* {
        char* r = p;
        p += (bytes + 255) & ~(size_t)255;
        return r;
    };
    const long NT = 32L * SEQ;  // 8192

    float* bias  = (float*)alloc(8L * SEQ * SEQ * 4);
    float* wln   = (float*)alloc((long)SEQ * DIM * 4);
    float* pq    = (float*)alloc((long)SEQ * DIM * 4);
    float* pk    = (float*)alloc((long)SEQ * DIM * 4);
    bf16*  xb    = (bf16*) alloc(NT * DIM * 2);
    bf16*  qkv   = (bf16*) alloc(NT * 2304 * 2);
    bf16*  ob    = (bf16*) alloc(NT * DIM * 2);
    float* xf    = (float*)alloc(NT * DIM * 4);
    bf16*  wqkv  = (bf16*) alloc(6L * 2304 * 768 * 2);
    bf16*  wo    = (bf16*) alloc(6L * 768 * 768 * 2);
    float* bqkv  = (float*)alloc(6L * 2304 * 4);

    const float SCALE = 0.07216878364870322f;   // (HD*2)^-0.5

    // weight conversion (bf16, q-scale folded)
    convert_qkv_kernel<<<(6L * 2304 * 768 / 4 + 255) / 256, 256, 0, stream>>>(Wq, Wk, Wv, wqkv, SCALE);
    convert_wo_kernel<<<(6L * 768 * 768 / 4 + 255) / 256, 256, 0, stream>>>(Wo, wo);
    convert_bias_kernel<<<(6 * 2304 + 255) / 256, 256, 0, stream>>>(bq, bk, bv, bqkv, SCALE);

    // positional bias precompute (f32)
    posln_kernel<<<256, 256, 0, stream>>>(pos_emb, pos_ln_g, pos_ln_b, wln);
    gemm_kernel<<<dim3(12, 4, 1), 256, 0, stream>>>(wln, DIM, 0, pos_q_w, DIM, 0, pos_q_b,
                                                    pq, DIM, 0, SEQ, DIM, DIM, SCALE);
    gemm_kernel<<<dim3(12, 4, 1), 256, 0, stream>>>(wln, DIM, 0, pos_k_w, DIM, 0, pos_k_b,
                                                    pk, DIM, 0, SEQ, DIM, DIM, 1.0f);
    gemm_kernel<<<dim3(4, 4, NH), 256, 0, stream>>>(pq, DIM, HD, pk, DIM, HD, nullptr,
                                                    bias, SEQ, (long)SEQ * SEQ, SEQ, SEQ, HD, 1.0f);
    relbias_kernel<<<256, 256, 0, stream>>>(rel_tab, rp, bias);

    // token embedding -> bf16
    gather_bf16_kernel<<<8192, 192, 0, stream>>>(tokens, embed, xb);

    for (int l = 0; l < 6; l++) {
        const bf16* wq_l = wqkv + (long)l * 2304 * 768;
        const bf16* wo_l = wo + (long)l * 768 * 768;
        const float* bq_l = bqkv + (long)l * 2304;
        const float* bo_l = bo + (long)l * 768;

        gemm_bf16_kernel<<<dim3(18, 64), 256, 0, stream>>>(xb, wq_l, bq_l, qkv, nullptr, 2304, 768);
        attn_mfma_kernel<<<1024, 256, 0, stream>>>(qkv, bias, ob);
        if (l < 5)
            gemm_bf16_kernel<<<dim3(6, 64), 256, 0, stream>>>(ob, wo_l, bo_l, xb, nullptr, 768, 768);
        else
            gemm_bf16_kernel<<<dim3(6, 64), 256, 0, stream>>>(ob, wo_l, bo_l, nullptr, xf, 768, 768);
    }

    out_kernel<<<32, 256, 0, stream>>>(xf, out);
}

// Round 3
// 923.105 us; speedup vs baseline: 6.5026x; 1.2471x over previous
//
#include <hip/hip_runtime.h>
#include <hip/hip_bf16.h>
#include <math.h>

constexpr int SEQ = 256;
constexpr int DIM = 768;
constexpr int NH  = 8;
constexpr int HD  = 96;

typedef __attribute__((ext_vector_type(8))) short short8;
typedef __attribute__((ext_vector_type(4))) float f32x4;
using bf16 = __hip_bfloat16;

#define ASYNC_COPY16(gptr, lptr) \
  __builtin_amdgcn_global_load_lds((const __attribute__((address_space(1))) void*)(gptr), \
                                   (__attribute__((address_space(3))) void*)(lptr), 16, 0, 0)

// ---------------------------------------------------------------------------
// f32 tiled GEMM (tiny positional-bias precompute only)
// ---------------------------------------------------------------------------
__global__ __launch_bounds__(256) void gemm_kernel(
    const float* __restrict__ A, int lda, long aoz,
    const float* __restrict__ W, int ldw, long woz,
    const float* __restrict__ bias,
    float* __restrict__ C, int ldc, long coz,
    int M, int N, int K, float scale)
{
    A += (long)blockIdx.z * aoz;
    W += (long)blockIdx.z * woz;
    C += (long)blockIdx.z * coz;

    __shared__ float As[16][68];
    __shared__ float Ws[16][68];

    const int bm = blockIdx.y * 64;
    const int bn = blockIdx.x * 64;
    const int tid = threadIdx.x;
    const int tx = tid & 15;
    const int ty = tid >> 4;

    float acc[4][4] = {};

    for (int k0 = 0; k0 < K; k0 += 16) {
#pragma unroll
        for (int i = 0; i < 4; i++) {
            int idx = tid + i * 256;
            int r = idx >> 4, c = idx & 15;
            As[c][r] = A[(long)(bm + r) * lda + (k0 + c)];
            Ws[c][r] = W[(long)(bn + r) * ldw + (k0 + c)];
        }
        __syncthreads();
#pragma unroll
        for (int kk = 0; kk < 16; kk++) {
            const float4 a = *(const float4*)&As[kk][ty * 4];
            const float4 w = *(const float4*)&Ws[kk][tx * 4];
            acc[0][0] += a.x * w.x; acc[0][1] += a.x * w.y; acc[0][2] += a.x * w.z; acc[0][3] += a.x * w.w;
            acc[1][0] += a.y * w.x; acc[1][1] += a.y * w.y; acc[1][2] += a.y * w.z; acc[1][3] += a.y * w.w;
            acc[2][0] += a.z * w.x; acc[2][1] += a.z * w.y; acc[2][2] += a.z * w.z; acc[2][3] += a.z * w.w;
            acc[3][0] += a.w * w.x; acc[3][1] += a.w * w.y; acc[3][2] += a.w * w.z; acc[3][3] += a.w * w.w;
        }
        __syncthreads();
    }

    const int n0 = bn + tx * 4;
    float4 bv = make_float4(0.f, 0.f, 0.f, 0.f);
    if (bias) bv = *(const float4*)&bias[n0];
#pragma unroll
    for (int i = 0; i < 4; i++) {
        const int m = bm + ty * 4 + i;
        float4 r;
        r.x = (acc[i][0] + bv.x) * scale;
        r.y = (acc[i][1] + bv.y) * scale;
        r.z = (acc[i][2] + bv.z) * scale;
        r.w = (acc[i][3] + bv.w) * scale;
        *(float4*)&C[(long)m * ldc + n0] = r;
    }
}

// ---------------------------------------------------------------------------
// LayerNorm of pos_emb rows
// ---------------------------------------------------------------------------
__global__ __launch_bounds__(256) void posln_kernel(
    const float* __restrict__ pe, const float* __restrict__ g,
    const float* __restrict__ bb, float* __restrict__ w)
{
    __shared__ float buf[256];
    const int i = blockIdx.x, tid = threadIdx.x;
    const float* row = pe + (long)i * DIM;
    float v0 = row[tid], v1 = row[tid + 256], v2 = row[tid + 512];

    buf[tid] = v0 + v1 + v2;
    __syncthreads();
    for (int off = 128; off > 0; off >>= 1) {
        if (tid < off) buf[tid] += buf[tid + off];
        __syncthreads();
    }
    const float mean = buf[0] * (1.f / 768.f);
    __syncthreads();

    const float d0 = v0 - mean, d1 = v1 - mean, d2 = v2 - mean;
    buf[tid] = d0 * d0 + d1 * d1 + d2 * d2;
    __syncthreads();
    for (int off = 128; off > 0; off >>= 1) {
        if (tid < off) buf[tid] += buf[tid + off];
        __syncthreads();
    }
    const float rstd = rsqrtf(buf[0] * (1.f / 768.f) + 1e-5f);

    float* wr = w + (long)i * DIM;
    wr[tid]       = d0 * rstd * g[tid]       + bb[tid];
    wr[tid + 256] = d1 * rstd * g[tid + 256] + bb[tid + 256];
    wr[tid + 512] = d2 * rstd * g[tid + 512] + bb[tid + 512];
}

// bias[h, ij] += table[rp[ij], h]
__global__ __launch_bounds__(256) void relbias_kernel(
    const float* __restrict__ table, const int* __restrict__ rp,
    float* __restrict__ bias)
{
    const int ij = blockIdx.x * 256 + threadIdx.x;
    const int bucket = rp[ij];
#pragma unroll
    for (int h = 0; h < NH; h++)
        bias[(long)h * SEQ * SEQ + ij] += table[bucket * NH + h];
}

// ---------------------------------------------------------------------------
// weight / bias conversion to bf16 (q-scale folded)
// ---------------------------------------------------------------------------
__global__ __launch_bounds__(256) void convert_qkv_kernel(
    const float* __restrict__ Wq, const float* __restrict__ Wk,
    const float* __restrict__ Wv, bf16* __restrict__ wqkv, float scale)
{
    const long idx = (long)blockIdx.x * 256 + threadIdx.x; // over 6*2304*768/4
    const long e = idx * 4;
    const int k = (int)(e % 768);
    const long nl = e / 768;
    const int n = (int)(nl % 2304);
    const int l = (int)(nl / 2304);

    const float* src;
    float sc = 1.f;
    if (n < 768)       { src = Wq + ((long)l * 768 + n) * 768; sc = scale; }
    else if (n < 1536) { src = Wk + ((long)l * 768 + (n - 768)) * 768; }
    else               { src = Wv + ((long)l * 768 + (n - 1536)) * 768; }

    const float4 v = *(const float4*)&src[k];
    bf16 tmp[4];
    tmp[0] = __float2bfloat16(v.x * sc);
    tmp[1] = __float2bfloat16(v.y * sc);
    tmp[2] = __float2bfloat16(v.z * sc);
    tmp[3] = __float2bfloat16(v.w * sc);
    *(uint2*)&wqkv[((long)l * 2304 + n) * 768 + k] = *(uint2*)tmp;
}

__global__ __launch_bounds__(256) void convert_wo_kernel(
    const float* __restrict__ Wo, bf16* __restrict__ wo)
{
    const long idx = (long)blockIdx.x * 256 + threadIdx.x; // over 6*768*768/4
    const long e = idx * 4;
    const float4 v = *(const float4*)&Wo[e];
    bf16 tmp[4];
    tmp[0] = __float2bfloat16(v.x);
    tmp[1] = __float2bfloat16(v.y);
    tmp[2] = __float2bfloat16(v.z);
    tmp[3] = __float2bfloat16(v.w);
    *(uint2*)&wo[e] = *(uint2*)tmp;
}

__global__ __launch_bounds__(256) void convert_bias_kernel(
    const float* __restrict__ bq, const float* __restrict__ bk,
    const float* __restrict__ bv, float* __restrict__ bqkv, float scale)
{
    const int idx = blockIdx.x * 256 + threadIdx.x; // over 6*2304
    const int n = idx % 2304;
    const int l = idx / 2304;
    float v;
    if (n < 768)       v = bq[l * 768 + n] * scale;
    else if (n < 1536) v = bk[l * 768 + (n - 768)];
    else               v = bv[l * 768 + (n - 1536)];
    bqkv[idx] = v;
}

// x_bf[t,:] = bf16(embed[tokens[t],:])
__global__ __launch_bounds__(192) void gather_bf16_kernel(
    const int* __restrict__ tokens, const float* __restrict__ emb,
    bf16* __restrict__ x)
{
    const int t = blockIdx.x;
    const int tok = tokens[t];
    const float4 v = ((const float4*)(emb + (long)tok * DIM))[threadIdx.x];
    bf16 tmp[4];
    tmp[0] = __float2bfloat16(v.x);
    tmp[1] = __float2bfloat16(v.y);
    tmp[2] = __float2bfloat16(v.z);
    tmp[3] = __float2bfloat16(v.w);
    *(uint2*)&x[(long)t * DIM + threadIdx.x * 4] = *(uint2*)tmp;
}

// ---------------------------------------------------------------------------
// bf16 MFMA GEMM: C[m,n] = sum_k A[m,k]*B[n,k] + bias[n]
// 128x128 tile, BK=64 (12 iters at K=768), 256 threads (4 waves, 64x64 each).
// XOR-swizzled LDS staging (conflict-free ds_read_b128) via global_load_lds.
// XCD M-stripe block swizzle for L2 locality (requires gridDim.y % 8 == 0).
// ---------------------------------------------------------------------------
__global__ __launch_bounds__(256) void gemm_bf16_kernel(
    const bf16* __restrict__ A, const bf16* __restrict__ B,
    const float* __restrict__ bias,
    bf16* __restrict__ Cb, float* __restrict__ Cf,
    int N, int K)
{
    __shared__ bf16 As[128 * 64];   // 16 KB each
    __shared__ bf16 Bs[128 * 64];

    const int tid = threadIdx.x;
    const int lane = tid & 63, wave = tid >> 6;
    const int wm = wave & 1, wn = wave >> 1;

    // XCD-aware swizzle: id%8 = XCD slot owns an 8-tile M-stripe.
    const int id = blockIdx.x + gridDim.x * blockIdx.y;
    const int xcd = id & 7, loc = id >> 3;
    const int bmt = xcd * 8 + (loc & 7);     // m-tile (gridDim.y==64)
    const int bnt = loc >> 3;                // n-tile
    const long bm = (long)bmt * 128, bn = (long)bnt * 128;

    const int col = lane & 15, quad = lane >> 4;

    f32x4 acc[4][4] = {};

    for (int k0 = 0; k0 < K; k0 += 64) {
        __syncthreads();
#pragma unroll
        for (int i = 0; i < 4; i++) {
            const int u = tid + i * 256;            // 0..1023
            const int r = u >> 3, c = u & 7;
            const int ca = c ^ (r & 7);             // swizzled k-chunk
            ASYNC_COPY16(A + (bm + r) * (long)K + k0 + ca * 8, &As[u * 8]);
            ASYNC_COPY16(B + (bn + r) * (long)K + k0 + ca * 8, &Bs[u * 8]);
        }
        __syncthreads();

#pragma unroll
        for (int ks = 0; ks < 2; ks++) {
            const int cc = ks * 4 + quad;           // content k-chunk
            short8 af[4], bfr[4];
#pragma unroll
            for (int t = 0; t < 4; t++) {
                const int ra = wm * 64 + t * 16 + col;
                const int rb = wn * 64 + t * 16 + col;
                af[t]  = *(const short8*)&As[ra * 64 + ((cc ^ (ra & 7)) * 8)];
                bfr[t] = *(const short8*)&Bs[rb * 64 + ((cc ^ (rb & 7)) * 8)];
            }
#pragma unroll
            for (int tm = 0; tm < 4; tm++)
#pragma unroll
                for (int tn = 0; tn < 4; tn++)
                    acc[tm][tn] = __builtin_amdgcn_mfma_f32_16x16x32_bf16(af[tm], bfr[tn], acc[tm][tn], 0, 0, 0);
        }
    }

#pragma unroll
    for (int tn = 0; tn < 4; tn++) {
        const long n = bn + wn * 64 + tn * 16 + col;
        const float bvv = bias[n];
#pragma unroll
        for (int tm = 0; tm < 4; tm++) {
#pragma unroll
            for (int r = 0; r < 4; r++) {
                const long m = bm + wm * 64 + tm * 16 + quad * 4 + r;
                const float v = acc[tm][tn][r] + bvv;
                if (Cf) Cf[m * N + n] = v;
                else    Cb[m * N + n] = __float2bfloat16(v);
            }
        }
    }
}

// ---------------------------------------------------------------------------
// MFMA attention: block per (it, h, b) with b innermost (bias L2 reuse).
// Q fragments in registers; LDS = Ks (13.3KB, aliased as Vt) + Ps (33.8KB).
// ---------------------------------------------------------------------------
__global__ __launch_bounds__(256) void attn_mfma_kernel(
    const bf16* __restrict__ qkv, const float* __restrict__ bias,
    bf16* __restrict__ o)
{
    constexpr int KSD = 104;  // Ks stride
    constexpr int PS  = 264;  // Ps stride
    constexpr int VS  = 40;   // Vt stride

    __shared__ bf16 Ks[64 * KSD];
    __shared__ bf16 Ps[64 * PS];
    bf16* Vt = Ks;            // 96*40 = 3840 < 6656

    const int blk = blockIdx.x;          // 4*8*32
    const int b  = blk & 31;
    const int h  = (blk >> 5) & 7;
    const int it = blk >> 8;
    const int i0 = it * 64;
    const int tid = threadIdx.x, lane = tid & 63, wave = tid >> 6;
    const int col = lane & 15, quad = lane >> 4;
    const long rowbase = (long)b * SEQ;

    // Q fragments straight from global (A-operand layout), once per block
    short8 aq[3];
    {
        const bf16* qrow = qkv + (rowbase + i0 + wave * 16 + col) * 2304 + h * 96;
#pragma unroll
        for (int ks = 0; ks < 3; ks++)
            aq[ks] = *(const short8*)&qrow[ks * 32 + quad * 8];
    }

    // ---- scores ----
    f32x4 accS[16] = {};
    for (int jc = 0; jc < 4; jc++) {
        __syncthreads();
        for (int u = tid; u < 768; u += 256) {
            const int r = u / 12, c8 = u % 12;
            *(uint4*)&Ks[r * KSD + c8 * 8] =
                *(const uint4*)&qkv[(rowbase + jc * 64 + r) * 2304 + 768 + h * 96 + c8 * 8];
        }
        __syncthreads();
#pragma unroll
        for (int ks = 0; ks < 3; ks++) {
#pragma unroll
            for (int jt = 0; jt < 4; jt++) {
                const short8 bk_ = *(const short8*)&Ks[(jt * 16 + col) * KSD + ks * 32 + quad * 8];
                accS[jc * 4 + jt] = __builtin_amdgcn_mfma_f32_16x16x32_bf16(aq[ks], bk_, accS[jc * 4 + jt], 0, 0, 0);
            }
        }
    }

    // ---- bias + softmax ----
    const float* bb = bias + ((long)h * SEQ + i0 + wave * 16 + quad * 4) * SEQ;
#pragma unroll
    for (int jt = 0; jt < 16; jt++)
#pragma unroll
        for (int r = 0; r < 4; r++)
            accS[jt][r] += bb[r * SEQ + jt * 16 + col];

#pragma unroll
    for (int r = 0; r < 4; r++) {
        float m = accS[0][r];
#pragma unroll
        for (int jt = 1; jt < 16; jt++) m = fmaxf(m, accS[jt][r]);
        for (int d = 1; d < 16; d <<= 1) m = fmaxf(m, __shfl_xor(m, d));
        float s = 0.f;
#pragma unroll
        for (int jt = 0; jt < 16; jt++) {
            const float e = __expf(accS[jt][r] - m);
            accS[jt][r] = e;
            s += e;
        }
        for (int d = 1; d < 16; d <<= 1) s += __shfl_xor(s, d);
        const float inv = 1.f / s;
        const int prow = wave * 16 + quad * 4 + r;
#pragma unroll
        for (int jt = 0; jt < 16; jt++)
            Ps[prow * PS + jt * 16 + col] = __float2bfloat16(accS[jt][r] * inv);
    }

    // ---- O = P.V ----
    f32x4 accO[6] = {};
    for (int kc = 0; kc < 8; kc++) {
        __syncthreads();
        for (int u = tid; u < 384; u += 256) {
            const int d = u % 96, jq = u / 96;
            bf16 tmp[8];
#pragma unroll
            for (int e = 0; e < 8; e++)
                tmp[e] = qkv[(rowbase + kc * 32 + jq * 8 + e) * 2304 + 1536 + h * 96 + d];
            *(uint4*)&Vt[d * VS + jq * 8] = *(uint4*)tmp;
        }
        __syncthreads();
        const short8 ap = *(const short8*)&Ps[(wave * 16 + col) * PS + kc * 32 + quad * 8];
#pragma unroll
        for (int nt = 0; nt < 6; nt++) {
            const short8 bv_ = *(const short8*)&Vt[(nt * 16 + col) * VS + quad * 8];
            accO[nt] = __builtin_amdgcn_mfma_f32_16x16x32_bf16(ap, bv_, accO[nt], 0, 0, 0);
        }
    }

#pragma unroll
    for (int nt = 0; nt < 6; nt++)
#pragma unroll
        for (int r = 0; r < 4; r++) {
            const long m = rowbase + i0 + wave * 16 + quad * 4 + r;
            o[m * DIM + h * 96 + nt * 16 + col] = __float2bfloat16(accO[nt][r]);
        }
}

// out[b,:] = xf[b, 0, :]
__global__ __launch_bounds__(256) void out_kernel(
    const float* __restrict__ x, float* __restrict__ out)
{
    const int b = blockIdx.x, tid = threadIdx.x;
    out[b * DIM + tid]       = x[(long)b * SEQ * DIM + tid];
    out[b * DIM + tid + 256] = x[(long)b * SEQ * DIM + tid + 256];
    out[b * DIM + tid + 512] = x[(long)b * SEQ * DIM + tid + 512];
}

extern "C" void kernel_launch(void* const* d_in, const int* in_sizes, int n_in,
                              void* d_out, int out_size, void* d_ws, size_t ws_size,
                              hipStream_t stream)
{
    const int*   tokens   = (const int*)d_in[0];
    const float* embed    = (const float*)d_in[1];
    const float* pos_emb  = (const float*)d_in[2];
    const float* pos_q_w  = (const float*)d_in[3];
    const float* pos_q_b  = (const float*)d_in[4];
    const float* pos_k_w  = (const float*)d_in[5];
    const float* pos_k_b  = (const float*)d_in[6];
    const float* pos_ln_g = (const float*)d_in[7];
    const float* pos_ln_b = (const float*)d_in[8];
    const float* rel_tab  = (const float*)d_in[9];
    const int*   rp       = (const int*)d_in[10];
    const float* Wq = (const float*)d_in[11];
    const float* bq = (const float*)d_in[12];
    const float* Wk = (const float*)d_in[13];
    const float* bk = (const float*)d_in[14];
    const float* Wv = (const float*)d_in[15];
    const float* bv = (const float*)d_in[16];
    const float* Wo = (const float*)d_in[17];
    const float* bo = (const float*)d_in[18];
    float* out = (float*)d_out;

    char* p = (char*)d_ws;
    auto alloc = [&](size_t bytes) -> char* {
        char* r = p;
        p += (bytes + 255) & ~(size_t)255;
        return r;
    };
    const long NT = 32L * SEQ;  // 8192

    float* bias  = (float*)alloc(8L * SEQ * SEQ * 4);
    float* wln   = (float*)alloc((long)SEQ * DIM * 4);
    float* pq    = (float*)alloc((long)SEQ * DIM * 4);
    float* pk    = (float*)alloc((long)SEQ * DIM * 4);
    bf16*  xb    = (bf16*) alloc(NT * DIM * 2);
    bf16*  qkv   = (bf16*) alloc(NT * 2304 * 2);
    bf16*  ob    = (bf16*) alloc(NT * DIM * 2);
    float* xf    = (float*)alloc(NT * DIM * 4);
    bf16*  wqkv  = (bf16*) alloc(6L * 2304 * 768 * 2);
    bf16*  wo    = (bf16*) alloc(6L * 768 * 768 * 2);
    float* bqkv  = (float*)alloc(6L * 2304 * 4);

    const float SCALE = 0.07216878364870322f;   // (HD*2)^-0.5

    // weight conversion (bf16, q-scale folded)
    convert_qkv_kernel<<<(6L * 2304 * 768 / 4 + 255) / 256, 256, 0, stream>>>(Wq, Wk, Wv, wqkv, SCALE);
    convert_wo_kernel<<<(6L * 768 * 768 / 4 + 255) / 256, 256, 0, stream>>>(Wo, wo);
    convert_bias_kernel<<<(6 * 2304 + 255) / 256, 256, 0, stream>>>(bq, bk, bv, bqkv, SCALE);

    // positional bias precompute (f32)
    posln_kernel<<<256, 256, 0, stream>>>(pos_emb, pos_ln_g, pos_ln_b, wln);
    gemm_kernel<<<dim3(12, 4, 1), 256, 0, stream>>>(wln, DIM, 0, pos_q_w, DIM, 0, pos_q_b,
                                                    pq, DIM, 0, SEQ, DIM, DIM, SCALE);
    gemm_kernel<<<dim3(12, 4, 1), 256, 0, stream>>>(wln, DIM, 0, pos_k_w, DIM, 0, pos_k_b,
                                                    pk, DIM, 0, SEQ, DIM, DIM, 1.0f);
    gemm_kernel<<<dim3(4, 4, NH), 256, 0, stream>>>(pq, DIM, HD, pk, DIM, HD, nullptr,
                                                    bias, SEQ, (long)SEQ * SEQ, SEQ, SEQ, HD, 1.0f);
    relbias_kernel<<<256, 256, 0, stream>>>(rel_tab, rp, bias);

    // token embedding -> bf16
    gather_bf16_kernel<<<8192, 192, 0, stream>>>(tokens, embed, xb);

    for (int l = 0; l < 6; l++) {
        const bf16* wq_l = wqkv + (long)l * 2304 * 768;
        const bf16* wo_l = wo + (long)l * 768 * 768;
        const float* bq_l = bqkv + (long)l * 2304;
        const float* bo_l = bo + (long)l * 768;

        gemm_bf16_kernel<<<dim3(18, 64), 256, 0, stream>>>(xb, wq_l, bq_l, qkv, nullptr, 2304, 768);
        attn_mfma_kernel<<<1024, 256, 0, stream>>>(qkv, bias, ob);
        if (l < 5)
            gemm_bf16_kernel<<<dim3(6, 64), 256, 0, stream>>>(ob, wo_l, bo_l, xb, nullptr, 768, 768);
        else
            gemm_bf16_kernel<<<dim3(6, 64), 256, 0, stream>>>(ob, wo_l, bo_l, nullptr, xf, 768, 768);
    }

    out_kernel<<<32, 256, 0, stream>>>(xf, out);
}